// Round 7
// baseline (409.258 us; speedup 1.0000x reference)
//
#include <hip/hip_runtime.h>

#define H 64
#define NOBJ 512
#define BATCH 128
#define PACK_BLOCKS ((BATCH * NOBJ * NOBJ) / 1024)   // 16384

typedef __attribute__((ext_vector_type(8))) short s16x8;
typedef __attribute__((ext_vector_type(4))) float f32x4;
typedef __attribute__((ext_vector_type(4))) unsigned short u16x4;
typedef __attribute__((ext_vector_type(8))) unsigned short u16x8;

__device__ __forceinline__ unsigned short f2bf(float f) {
    unsigned int u = __float_as_uint(f);
    u += 0x7FFFu + ((u >> 16) & 1u);          // round-to-nearest-even
    return (unsigned short)(u >> 16);
}
__device__ __forceinline__ float bf2f(unsigned short h) {
    return __uint_as_float((unsigned int)h << 16);
}

#define MFMA16(a, b, c) __builtin_amdgcn_mfma_f32_16x16x32_bf16(a, b, c, 0, 0, 0)

// ---------------- Kernel 1: fused prep = mask-pack + MFMA projections ----------
// flat grid: blocks [0, 16384) pack mask {0.0,1.0} -> bits (134 MB -> 4.2 MB);
// blocks [16384, 19456) do the q/k/v projections (z = (gid-16384)>>10).
__global__ __launch_bounds__(256) void prep_kernel(
    const float* __restrict__ mask, unsigned int* __restrict__ bits,
    const float* __restrict__ q, const float* __restrict__ k, const float* __restrict__ v,
    const float* __restrict__ Wq, const float* __restrict__ bq,
    const float* __restrict__ Wk, const float* __restrict__ bk,
    const float* __restrict__ Wv, const float* __restrict__ bv,
    unsigned short* __restrict__ qh, unsigned short* __restrict__ ql,
    unsigned short* __restrict__ kh, unsigned short* __restrict__ kl,
    unsigned short* __restrict__ vt)
{
    __shared__ unsigned short vtile[64][72];   // proj: [h][n] tile; pack: nibble buf
    const int tid = threadIdx.x;

    if (blockIdx.x < PACK_BLOCKS) {
        // ---- mask pack: 1024 floats/block ----
        unsigned char* nib = (unsigned char*)&vtile[0][0];
        const size_t base = (size_t)blockIdx.x * 1024;
        const f32x4 f = __builtin_nontemporal_load((const f32x4*)(mask + base + (size_t)tid * 4));
        nib[tid] = (unsigned char)((unsigned)(f[0] != 0.0f)
                 | ((unsigned)(f[1] != 0.0f) << 1)
                 | ((unsigned)(f[2] != 0.0f) << 2)
                 | ((unsigned)(f[3] != 0.0f) << 3));
        __syncthreads();
        if (tid < 32) {
            unsigned int wv = 0;
            #pragma unroll
            for (int i = 0; i < 8; ++i)
                wv |= (unsigned int)nib[tid * 8 + i] << (4 * i);
            bits[base / 32 + tid] = wv;
        }
        return;
    }

    // ---- projections ----
    const int p   = blockIdx.x - PACK_BLOCKS;
    const int z   = p >> 10;              // 0..2 = {q,k,v}
    const int rem = p & 1023;
    const int b   = rem >> 3;
    const int n0  = (rem & 7) * 64;

    const float* x; const float* W; const float* bias;
    unsigned short* yh; unsigned short* yl;
    if (z == 0)      { x = q; W = Wq; bias = bq; yh = qh; yl = ql; }
    else if (z == 1) { x = k; W = Wk; bias = bk; yh = kh; yl = kl; }
    else             { x = v; W = Wv; bias = bv; yh = nullptr; yl = nullptr; }

    const int lane = tid & 63;
    const int wt   = tid >> 6;
    const int l15  = lane & 15;
    const int lg   = lane >> 4;

    // W fragments: lane = (row ht*16+l15, k = kc*32+lg*8+j), k contiguous
    s16x8 wfh[4][2], wfl[4][2];
    #pragma unroll
    for (int ht = 0; ht < 4; ++ht) {
        #pragma unroll
        for (int kc = 0; kc < 2; ++kc) {
            const float* wp = W + (ht * 16 + l15) * H + kc * 32 + lg * 8;
            float4 f0 = *(const float4*)wp;
            float4 f1 = *(const float4*)(wp + 4);
            float f[8] = {f0.x, f0.y, f0.z, f0.w, f1.x, f1.y, f1.z, f1.w};
            s16x8 hi8, lo8;
            #pragma unroll
            for (int j = 0; j < 8; ++j) {
                const unsigned short hb = f2bf(f[j]);
                hi8[j] = (short)hb;
                lo8[j] = (short)f2bf(f[j] - bf2f(hb));
            }
            wfh[ht][kc] = hi8; wfl[ht][kc] = lo8;
        }
    }

    // x fragments: n = n0+wt*16+l15, x is [N,B,H]
    const int n = n0 + wt * 16 + l15;
    const float* xr = x + ((size_t)n * BATCH + b) * H;
    s16x8 xfh[2], xfl[2];
    #pragma unroll
    for (int kc = 0; kc < 2; ++kc) {
        const float* xp = xr + kc * 32 + lg * 8;
        float4 f0 = *(const float4*)xp;
        float4 f1 = *(const float4*)(xp + 4);
        float f[8] = {f0.x, f0.y, f0.z, f0.w, f1.x, f1.y, f1.z, f1.w};
        s16x8 hi8, lo8;
        #pragma unroll
        for (int j = 0; j < 8; ++j) {
            const unsigned short hb = f2bf(f[j]);
            hi8[j] = (short)hb;
            lo8[j] = (short)f2bf(f[j] - bf2f(hb));
        }
        xfh[kc] = hi8; xfl[kc] = lo8;
    }

    if (z < 2) {
        // D[h][n]: lane holds h = ht*16+lg*4+r, n fixed -> coalesced u16x4 stores
        #pragma unroll
        for (int ht = 0; ht < 4; ++ht) {
            const float4 b4 = *(const float4*)(bias + ht * 16 + lg * 4);
            f32x4 acc = {b4.x, b4.y, b4.z, b4.w};
            acc = MFMA16(wfh[ht][0], xfh[0], acc);
            acc = MFMA16(wfh[ht][1], xfh[1], acc);
            acc = MFMA16(wfh[ht][0], xfl[0], acc);
            acc = MFMA16(wfh[ht][1], xfl[1], acc);
            acc = MFMA16(wfl[ht][0], xfh[0], acc);
            acc = MFMA16(wfl[ht][1], xfh[1], acc);
            u16x4 hv, lv;
            #pragma unroll
            for (int r = 0; r < 4; ++r) {
                const unsigned short hb = f2bf(acc[r]);
                hv[r] = hb;
                lv[r] = f2bf(acc[r] - bf2f(hb));
            }
            const size_t o = ((size_t)b * NOBJ + n) * H + ht * 16 + lg * 4;
            *(u16x4*)(yh + o) = hv;
            *(u16x4*)(yl + o) = lv;
        }
    } else {
        // D[n][h] -> LDS tile -> coalesced vt [B,H,N] stores
        #pragma unroll
        for (int ht = 0; ht < 4; ++ht) {
            const float bs = bias[ht * 16 + l15];
            f32x4 acc = {bs, bs, bs, bs};
            acc = MFMA16(xfh[0], wfh[ht][0], acc);
            acc = MFMA16(xfh[1], wfh[ht][1], acc);
            acc = MFMA16(xfl[0], wfh[ht][0], acc);
            acc = MFMA16(xfl[1], wfh[ht][1], acc);
            acc = MFMA16(xfh[0], wfl[ht][0], acc);
            acc = MFMA16(xfh[1], wfl[ht][1], acc);
            u16x4 hv;
            #pragma unroll
            for (int r = 0; r < 4; ++r) hv[r] = f2bf(acc[r]);
            *(u16x4*)&vtile[ht * 16 + l15][wt * 16 + lg * 4] = hv;
        }
        __syncthreads();
        const int h = tid >> 2, nc = (tid & 3) * 16;
        const u16x8 d0 = *(const u16x8*)&vtile[h][nc];
        const u16x8 d1 = *(const u16x8*)&vtile[h][nc + 8];
        unsigned short* dst = vt + ((size_t)b * H + h) * NOBJ + n0 + nc;
        *(u16x8*)dst = d0;
        *(u16x8*)(dst + 8) = d1;
    }
}

// ---------------- Kernel 2: MFMA attention, XCD-colocated + 3-deep k ring ----
// 1-D grid 4096. Swizzle: xcd = orig&7, s = orig>>3, b = xcd + 8*(s>>5), nt = s&31
// (bijective) -> per-XCD read slice stays in its 4 MB L2 (FETCH 109->23.6 MB, R6).
// amdgpu_waves_per_eu(4,4): LDS caps us at 4 blocks/CU = 4 waves/SIMD anyway, so
// pin the allocator to that -> 128-VGPR budget -> k-ring + ev stay in registers
// (R6 showed the compiler's 64-VGPR choice sank the prefetch loads to use).
__global__ __launch_bounds__(256)
__attribute__((amdgpu_waves_per_eu(4, 4)))
void attn_kernel(
    const unsigned short* __restrict__ qh, const unsigned short* __restrict__ ql,
    const unsigned short* __restrict__ kh, const unsigned short* __restrict__ kl,
    const unsigned short* __restrict__ vt, const unsigned int* __restrict__ bits,
    float* __restrict__ out, float* __restrict__ Aout)
{
    __shared__ unsigned short sch[16][520];  // e hi strip, stride 260 dwords
    __shared__ unsigned short scl[16][520];  // e lo strip
    __shared__ float rsum[4][16];
    __shared__ float inv[16];

    const int tid  = threadIdx.x;
    const int lane = tid & 63;
    const int w    = tid >> 6;
    const int l15  = lane & 15;
    const int lg   = lane >> 4;

    const int orig = blockIdx.x;
    const int xcd  = orig & 7;
    const int s    = orig >> 3;
    const int b    = xcd + 8 * (s >> 5);
    const int n0   = (s & 31) * 16;

    // q fragments (B-operand): col n = l15, k = h contiguous
    const size_t qoff = ((size_t)b * NOBJ + n0 + l15) * H + lg * 8;
    const s16x8 qfh0 = *(const s16x8*)(qh + qoff);
    const s16x8 qfh1 = *(const s16x8*)(qh + qoff + 32);
    const s16x8 qfl0 = *(const s16x8*)(ql + qoff);
    const s16x8 qfl1 = *(const s16x8*)(ql + qoff + 32);

    const unsigned short* khp = kh + ((size_t)b * NOBJ + w * 128 + l15) * H + lg * 8;
    const unsigned short* klp = kl + ((size_t)b * NOBJ + w * 128 + l15) * H + lg * 8;

    // one uint4 = this row's mask bits for cols [w*128, w*128+128)
    const uint4 mw = *(const uint4*)(bits + ((size_t)b * NOBJ + n0 + l15) * (NOBJ / 32) + w * 4);
    const unsigned mwa[4] = {mw.x, mw.y, mw.z, mw.w};

    f32x4 ev[8];                 // exp(score)*mask kept in regs for the fp32 A-write
    float rp = 0.0f;

    // 3-buffer k-fragment ring, prefetch distance 2
    s16x8 ka[3][4];
#define LOADK(buf, mi)                                              \
    do {                                                            \
        const int _o = (mi) * 16 * H;                               \
        ka[buf][0] = *(const s16x8*)(khp + _o);                     \
        ka[buf][1] = *(const s16x8*)(khp + _o + 32);                \
        ka[buf][2] = *(const s16x8*)(klp + _o);                     \
        ka[buf][3] = *(const s16x8*)(klp + _o + 32);                \
    } while (0)

    LOADK(0, 0);
    LOADK(1, 1);

    #pragma unroll
    for (int mt = 0; mt < 8; ++mt) {
        const int cur = mt % 3;
        if (mt < 6) LOADK((mt + 2) % 3, mt + 2);

        f32x4 acc = {0.0f, 0.0f, 0.0f, 0.0f};           // C[m][n] = sum_h k[m][h] q[n][h]
        acc = MFMA16(ka[cur][0], qfh0, acc);
        acc = MFMA16(ka[cur][1], qfh1, acc);
        acc = MFMA16(ka[cur][0], qfl0, acc);
        acc = MFMA16(ka[cur][1], qfl1, acc);
        acc = MFMA16(ka[cur][2], qfh0, acc);
        acc = MFMA16(ka[cur][3], qfh1, acc);

        // mask bits for this mt: word mt>>1, bits (mt&1)*16 + lg*4 + r
        const unsigned wsel = mwa[mt >> 1] >> (((mt & 1) << 4) + (lg << 2));
        f32x4 e;
        #pragma unroll
        for (int r = 0; r < 4; ++r) {
            const float ex = __expf(acc[r] * 0.125f);
            e[r] = ((wsel >> r) & 1u) ? ex : 0.0f;
        }
        ev[mt] = e;
        rp += (e[0] + e[1]) + (e[2] + e[3]);

        u16x4 hv, lv;
        #pragma unroll
        for (int r = 0; r < 4; ++r) {
            const unsigned short hb = f2bf(e[r]);
            hv[r] = hb;
            lv[r] = f2bf(e[r] - bf2f(hb));
        }
        const int mo = w * 128 + mt * 16 + lg * 4;
        *(u16x4*)&sch[l15][mo] = hv;
        *(u16x4*)&scl[l15][mo] = lv;
    }
#undef LOADK

    rp += __shfl_xor(rp, 16);
    rp += __shfl_xor(rp, 32);
    if (lane < 16) rsum[w][lane] = rp;
    __syncthreads();
    if (tid < 16) {
        const float sv = (rsum[0][tid] + rsum[1][tid]) + (rsum[2][tid] + rsum[3][tid]);
        inv[tid] = 1.0f / (sv == 0.0f ? 1.0f : sv);
    }
    __syncthreads();

    // A write: fp32 from registers, float4 per lane (normal stores: L2 write-combines
    // the 8 x 64B row chunks into full lines; NT stores cost +33 MB at HBM, R6)
    {
        const float iv = inv[l15];
        float* Arow = Aout + ((size_t)b * NOBJ + n0 + l15) * NOBJ + w * 128 + lg * 4;
        #pragma unroll
        for (int mt = 0; mt < 8; ++mt) {
            float4 a4;
            a4.x = ev[mt][0] * iv; a4.y = ev[mt][1] * iv;
            a4.z = ev[mt][2] * iv; a4.w = ev[mt][3] * iv;
            *(float4*)(Arow + mt * 16) = a4;
        }
    }

    // AV: out[n][h] = inv[n] * sum_m e[n][m] * v[m][h]
    const unsigned short* vtp = vt + ((size_t)b * H + w * 16 + l15) * NOBJ + lg * 8;
    f32x4 o0 = {0.0f, 0.0f, 0.0f, 0.0f}, o1 = {0.0f, 0.0f, 0.0f, 0.0f};
    #pragma unroll
    for (int ks = 0; ks < 16; ks += 2) {
        const int mk = ks * 32 + lg * 8;
        const s16x8 ah0 = *(const s16x8*)&sch[l15][mk];
        const s16x8 al0 = *(const s16x8*)&scl[l15][mk];
        const s16x8 vf0 = *(const s16x8*)(vtp + ks * 32);
        o0 = MFMA16(ah0, vf0, o0);
        o0 = MFMA16(al0, vf0, o0);
        const s16x8 ah1 = *(const s16x8*)&sch[l15][mk + 32];
        const s16x8 al1 = *(const s16x8*)&scl[l15][mk + 32];
        const s16x8 vf1 = *(const s16x8*)(vtp + ks * 32 + 32);
        o1 = MFMA16(ah1, vf1, o1);
        o1 = MFMA16(al1, vf1, o1);
    }

    #pragma unroll
    for (int r = 0; r < 4; ++r) {
        const int nn = lg * 4 + r;                       // C row = n, col = h = l15
        out[((size_t)(n0 + nn) * BATCH + b) * H + w * 16 + l15] = (o0[r] + o1[r]) * inv[nn];
    }
}

extern "C" void kernel_launch(void* const* d_in, const int* in_sizes, int n_in,
                              void* d_out, int out_size, void* d_ws, size_t ws_size,
                              hipStream_t stream)
{
    (void)in_sizes; (void)n_in; (void)out_size; (void)ws_size;
    const float* q    = (const float*)d_in[0];
    const float* k    = (const float*)d_in[1];
    const float* v    = (const float*)d_in[2];
    const float* mask = (const float*)d_in[3];
    const float* Wq   = (const float*)d_in[4];
    const float* bq   = (const float*)d_in[5];
    const float* Wk   = (const float*)d_in[6];
    const float* bk   = (const float*)d_in[7];
    const float* Wv   = (const float*)d_in[8];
    const float* bv   = (const float*)d_in[9];

    float* out  = (float*)d_out;                                  // [N,B,H]
    float* Aout = (float*)d_out + (size_t)NOBJ * BATCH * H;       // [B,N,N]

    // workspace: 5 bf16 arrays (42 MB) + bitmask (4.2 MB)
    const size_t S = (size_t)BATCH * NOBJ * H;
    unsigned short* qh = (unsigned short*)d_ws;
    unsigned short* ql = qh + S;
    unsigned short* kh = ql + S;
    unsigned short* kl = kh + S;
    unsigned short* vt = kl + S;
    unsigned int* bits = (unsigned int*)(vt + S);

    prep_kernel<<<dim3(PACK_BLOCKS + 3 * BATCH * (NOBJ / 64)), 256, 0, stream>>>(
        mask, bits, q, k, v, Wq, bq, Wk, bk, Wv, bv, qh, ql, kh, kl, vt);
    attn_kernel<<<dim3((NOBJ / 16) * BATCH), 256, 0, stream>>>(
        qh, ql, kh, kl, vt, bits, out, Aout);
}

// Round 8
// 402.351 us; speedup vs baseline: 1.0172x; 1.0172x over previous
//
#include <hip/hip_runtime.h>

#define H 64
#define NOBJ 512
#define BATCH 128
#define PACK_BLOCKS ((BATCH * NOBJ * NOBJ) / 1024)   // 16384

typedef __attribute__((ext_vector_type(8))) short s16x8;
typedef __attribute__((ext_vector_type(4))) float f32x4;
typedef __attribute__((ext_vector_type(4))) unsigned short u16x4;
typedef __attribute__((ext_vector_type(8))) unsigned short u16x8;

__device__ __forceinline__ unsigned short f2bf(float f) {
    unsigned int u = __float_as_uint(f);
    u += 0x7FFFu + ((u >> 16) & 1u);          // round-to-nearest-even
    return (unsigned short)(u >> 16);
}
__device__ __forceinline__ float bf2f(unsigned short h) {
    return __uint_as_float((unsigned int)h << 16);
}

#define MFMA16(a, b, c) __builtin_amdgcn_mfma_f32_16x16x32_bf16(a, b, c, 0, 0, 0)

// ---------------- Kernel 1: fused prep = mask-pack + MFMA projections ----------
// flat grid: blocks [0, 16384) pack mask {0.0,1.0} -> bits (134 MB -> 4.2 MB);
// blocks [16384, 19456) do the q/k/v projections (z = (gid-16384)>>10).
__global__ __launch_bounds__(256) void prep_kernel(
    const float* __restrict__ mask, unsigned int* __restrict__ bits,
    const float* __restrict__ q, const float* __restrict__ k, const float* __restrict__ v,
    const float* __restrict__ Wq, const float* __restrict__ bq,
    const float* __restrict__ Wk, const float* __restrict__ bk,
    const float* __restrict__ Wv, const float* __restrict__ bv,
    unsigned short* __restrict__ qh, unsigned short* __restrict__ ql,
    unsigned short* __restrict__ kh, unsigned short* __restrict__ kl,
    unsigned short* __restrict__ vt)
{
    __shared__ unsigned short vtile[64][72];   // proj: [h][n] tile; pack: nibble buf
    const int tid = threadIdx.x;

    if (blockIdx.x < PACK_BLOCKS) {
        // ---- mask pack: 1024 floats/block ----
        unsigned char* nib = (unsigned char*)&vtile[0][0];
        const size_t base = (size_t)blockIdx.x * 1024;
        const f32x4 f = __builtin_nontemporal_load((const f32x4*)(mask + base + (size_t)tid * 4));
        nib[tid] = (unsigned char)((unsigned)(f[0] != 0.0f)
                 | ((unsigned)(f[1] != 0.0f) << 1)
                 | ((unsigned)(f[2] != 0.0f) << 2)
                 | ((unsigned)(f[3] != 0.0f) << 3));
        __syncthreads();
        if (tid < 32) {
            unsigned int wv = 0;
            #pragma unroll
            for (int i = 0; i < 8; ++i)
                wv |= (unsigned int)nib[tid * 8 + i] << (4 * i);
            bits[base / 32 + tid] = wv;
        }
        return;
    }

    // ---- projections ----
    const int p   = blockIdx.x - PACK_BLOCKS;
    const int z   = p >> 10;              // 0..2 = {q,k,v}
    const int rem = p & 1023;
    const int b   = rem >> 3;
    const int n0  = (rem & 7) * 64;

    const float* x; const float* W; const float* bias;
    unsigned short* yh; unsigned short* yl;
    if (z == 0)      { x = q; W = Wq; bias = bq; yh = qh; yl = ql; }
    else if (z == 1) { x = k; W = Wk; bias = bk; yh = kh; yl = kl; }
    else             { x = v; W = Wv; bias = bv; yh = nullptr; yl = nullptr; }

    const int lane = tid & 63;
    const int wt   = tid >> 6;
    const int l15  = lane & 15;
    const int lg   = lane >> 4;

    // W fragments: lane = (row ht*16+l15, k = kc*32+lg*8+j), k contiguous
    s16x8 wfh[4][2], wfl[4][2];
    #pragma unroll
    for (int ht = 0; ht < 4; ++ht) {
        #pragma unroll
        for (int kc = 0; kc < 2; ++kc) {
            const float* wp = W + (ht * 16 + l15) * H + kc * 32 + lg * 8;
            float4 f0 = *(const float4*)wp;
            float4 f1 = *(const float4*)(wp + 4);
            float f[8] = {f0.x, f0.y, f0.z, f0.w, f1.x, f1.y, f1.z, f1.w};
            s16x8 hi8, lo8;
            #pragma unroll
            for (int j = 0; j < 8; ++j) {
                const unsigned short hb = f2bf(f[j]);
                hi8[j] = (short)hb;
                lo8[j] = (short)f2bf(f[j] - bf2f(hb));
            }
            wfh[ht][kc] = hi8; wfl[ht][kc] = lo8;
        }
    }

    // x fragments: n = n0+wt*16+l15, x is [N,B,H]
    const int n = n0 + wt * 16 + l15;
    const float* xr = x + ((size_t)n * BATCH + b) * H;
    s16x8 xfh[2], xfl[2];
    #pragma unroll
    for (int kc = 0; kc < 2; ++kc) {
        const float* xp = xr + kc * 32 + lg * 8;
        float4 f0 = *(const float4*)xp;
        float4 f1 = *(const float4*)(xp + 4);
        float f[8] = {f0.x, f0.y, f0.z, f0.w, f1.x, f1.y, f1.z, f1.w};
        s16x8 hi8, lo8;
        #pragma unroll
        for (int j = 0; j < 8; ++j) {
            const unsigned short hb = f2bf(f[j]);
            hi8[j] = (short)hb;
            lo8[j] = (short)f2bf(f[j] - bf2f(hb));
        }
        xfh[kc] = hi8; xfl[kc] = lo8;
    }

    if (z < 2) {
        // D[h][n]: lane holds h = ht*16+lg*4+r, n fixed -> coalesced u16x4 stores
        #pragma unroll
        for (int ht = 0; ht < 4; ++ht) {
            const float4 b4 = *(const float4*)(bias + ht * 16 + lg * 4);
            f32x4 acc = {b4.x, b4.y, b4.z, b4.w};
            acc = MFMA16(wfh[ht][0], xfh[0], acc);
            acc = MFMA16(wfh[ht][1], xfh[1], acc);
            acc = MFMA16(wfh[ht][0], xfl[0], acc);
            acc = MFMA16(wfh[ht][1], xfl[1], acc);
            acc = MFMA16(wfl[ht][0], xfh[0], acc);
            acc = MFMA16(wfl[ht][1], xfh[1], acc);
            u16x4 hv, lv;
            #pragma unroll
            for (int r = 0; r < 4; ++r) {
                const unsigned short hb = f2bf(acc[r]);
                hv[r] = hb;
                lv[r] = f2bf(acc[r] - bf2f(hb));
            }
            const size_t o = ((size_t)b * NOBJ + n) * H + ht * 16 + lg * 4;
            *(u16x4*)(yh + o) = hv;
            *(u16x4*)(yl + o) = lv;
        }
    } else {
        // D[n][h] -> LDS tile -> coalesced vt [B,H,N] stores
        #pragma unroll
        for (int ht = 0; ht < 4; ++ht) {
            const float bs = bias[ht * 16 + l15];
            f32x4 acc = {bs, bs, bs, bs};
            acc = MFMA16(xfh[0], wfh[ht][0], acc);
            acc = MFMA16(xfh[1], wfh[ht][1], acc);
            acc = MFMA16(xfl[0], wfh[ht][0], acc);
            acc = MFMA16(xfl[1], wfh[ht][1], acc);
            acc = MFMA16(xfh[0], wfl[ht][0], acc);
            acc = MFMA16(xfh[1], wfl[ht][1], acc);
            u16x4 hv;
            #pragma unroll
            for (int r = 0; r < 4; ++r) hv[r] = f2bf(acc[r]);
            *(u16x4*)&vtile[ht * 16 + l15][wt * 16 + lg * 4] = hv;
        }
        __syncthreads();
        const int h = tid >> 2, nc = (tid & 3) * 16;
        const u16x8 d0 = *(const u16x8*)&vtile[h][nc];
        const u16x8 d1 = *(const u16x8*)&vtile[h][nc + 8];
        unsigned short* dst = vt + ((size_t)b * H + h) * NOBJ + n0 + nc;
        *(u16x8*)dst = d0;
        *(u16x8*)(dst + 8) = d1;
    }
}

// ---------------- Kernel 2: MFMA attention, XCD-colocated + 3-deep k ring ----
// 1-D grid 4096. Swizzle: xcd = orig&7, s = orig>>3, b = xcd + 8*(s>>5), nt = s&31
// (bijective) -> per-XCD read slice stays in its 4 MB L2 (FETCH 109->23.6 MB, R6).
// __launch_bounds__(256, 2): live state (ka ring 48 + ev 32 + q 16 + misc) needs
// ~110+ VGPRs; the (256,4) builds clamped to 64 and SPILLED to scratch (R4-R7:
// VGPR_Count=64, ~70K cyc/block vs ~7K modeled -> scratch VMEM in the chain).
// min-waves/EU=2 raises the cap to 256 (R1 precedent: same bound -> VGPR=100);
// LDS already caps residency at 4 blocks/CU, so no occupancy is lost.
__global__ __launch_bounds__(256, 2) void attn_kernel(
    const unsigned short* __restrict__ qh, const unsigned short* __restrict__ ql,
    const unsigned short* __restrict__ kh, const unsigned short* __restrict__ kl,
    const unsigned short* __restrict__ vt, const unsigned int* __restrict__ bits,
    float* __restrict__ out, float* __restrict__ Aout)
{
    __shared__ unsigned short sch[16][520];  // e hi strip, stride 260 dwords
    __shared__ unsigned short scl[16][520];  // e lo strip
    __shared__ float rsum[4][16];
    __shared__ float inv[16];

    const int tid  = threadIdx.x;
    const int lane = tid & 63;
    const int w    = tid >> 6;
    const int l15  = lane & 15;
    const int lg   = lane >> 4;

    const int orig = blockIdx.x;
    const int xcd  = orig & 7;
    const int s    = orig >> 3;
    const int b    = xcd + 8 * (s >> 5);
    const int n0   = (s & 31) * 16;

    // q fragments (B-operand): col n = l15, k = h contiguous
    const size_t qoff = ((size_t)b * NOBJ + n0 + l15) * H + lg * 8;
    const s16x8 qfh0 = *(const s16x8*)(qh + qoff);
    const s16x8 qfh1 = *(const s16x8*)(qh + qoff + 32);
    const s16x8 qfl0 = *(const s16x8*)(ql + qoff);
    const s16x8 qfl1 = *(const s16x8*)(ql + qoff + 32);

    const unsigned short* khp = kh + ((size_t)b * NOBJ + w * 128 + l15) * H + lg * 8;
    const unsigned short* klp = kl + ((size_t)b * NOBJ + w * 128 + l15) * H + lg * 8;

    // one uint4 = this row's mask bits for cols [w*128, w*128+128)
    const uint4 mw = *(const uint4*)(bits + ((size_t)b * NOBJ + n0 + l15) * (NOBJ / 32) + w * 4);
    const unsigned mwa[4] = {mw.x, mw.y, mw.z, mw.w};

    f32x4 ev[8];                 // exp(score)*mask kept in regs for the fp32 A-write
    float rp = 0.0f;

    // 3-buffer k-fragment ring, prefetch distance 2
    s16x8 ka[3][4];
#define LOADK(buf, mi)                                              \
    do {                                                            \
        const int _o = (mi) * 16 * H;                               \
        ka[buf][0] = *(const s16x8*)(khp + _o);                     \
        ka[buf][1] = *(const s16x8*)(khp + _o + 32);                \
        ka[buf][2] = *(const s16x8*)(klp + _o);                     \
        ka[buf][3] = *(const s16x8*)(klp + _o + 32);                \
    } while (0)

    LOADK(0, 0);
    LOADK(1, 1);

    #pragma unroll
    for (int mt = 0; mt < 8; ++mt) {
        const int cur = mt % 3;
        if (mt < 6) LOADK((mt + 2) % 3, mt + 2);

        f32x4 acc = {0.0f, 0.0f, 0.0f, 0.0f};           // C[m][n] = sum_h k[m][h] q[n][h]
        acc = MFMA16(ka[cur][0], qfh0, acc);
        acc = MFMA16(ka[cur][1], qfh1, acc);
        acc = MFMA16(ka[cur][0], qfl0, acc);
        acc = MFMA16(ka[cur][1], qfl1, acc);
        acc = MFMA16(ka[cur][2], qfh0, acc);
        acc = MFMA16(ka[cur][3], qfh1, acc);

        // mask bits for this mt: word mt>>1, bits (mt&1)*16 + lg*4 + r
        const unsigned wsel = mwa[mt >> 1] >> (((mt & 1) << 4) + (lg << 2));
        f32x4 e;
        #pragma unroll
        for (int r = 0; r < 4; ++r) {
            const float ex = __expf(acc[r] * 0.125f);
            e[r] = ((wsel >> r) & 1u) ? ex : 0.0f;
        }
        ev[mt] = e;
        rp += (e[0] + e[1]) + (e[2] + e[3]);

        u16x4 hv, lv;
        #pragma unroll
        for (int r = 0; r < 4; ++r) {
            const unsigned short hb = f2bf(e[r]);
            hv[r] = hb;
            lv[r] = f2bf(e[r] - bf2f(hb));
        }
        const int mo = w * 128 + mt * 16 + lg * 4;
        *(u16x4*)&sch[l15][mo] = hv;
        *(u16x4*)&scl[l15][mo] = lv;
    }
#undef LOADK

    rp += __shfl_xor(rp, 16);
    rp += __shfl_xor(rp, 32);
    if (lane < 16) rsum[w][lane] = rp;
    __syncthreads();
    if (tid < 16) {
        const float sv = (rsum[0][tid] + rsum[1][tid]) + (rsum[2][tid] + rsum[3][tid]);
        inv[tid] = 1.0f / (sv == 0.0f ? 1.0f : sv);
    }
    __syncthreads();

    // A write: fp32 from registers, float4 per lane (normal stores: L2 write-combines)
    {
        const float iv = inv[l15];
        float* Arow = Aout + ((size_t)b * NOBJ + n0 + l15) * NOBJ + w * 128 + lg * 4;
        #pragma unroll
        for (int mt = 0; mt < 8; ++mt) {
            float4 a4;
            a4.x = ev[mt][0] * iv; a4.y = ev[mt][1] * iv;
            a4.z = ev[mt][2] * iv; a4.w = ev[mt][3] * iv;
            *(float4*)(Arow + mt * 16) = a4;
        }
    }

    // AV: out[n][h] = inv[n] * sum_m e[n][m] * v[m][h]
    const unsigned short* vtp = vt + ((size_t)b * H + w * 16 + l15) * NOBJ + lg * 8;
    f32x4 o0 = {0.0f, 0.0f, 0.0f, 0.0f}, o1 = {0.0f, 0.0f, 0.0f, 0.0f};
    #pragma unroll
    for (int ks = 0; ks < 16; ks += 2) {
        const int mk = ks * 32 + lg * 8;
        const s16x8 ah0 = *(const s16x8*)&sch[l15][mk];
        const s16x8 al0 = *(const s16x8*)&scl[l15][mk];
        const s16x8 vf0 = *(const s16x8*)(vtp + ks * 32);
        o0 = MFMA16(ah0, vf0, o0);
        o0 = MFMA16(al0, vf0, o0);
        const s16x8 ah1 = *(const s16x8*)&sch[l15][mk + 32];
        const s16x8 al1 = *(const s16x8*)&scl[l15][mk + 32];
        const s16x8 vf1 = *(const s16x8*)(vtp + ks * 32 + 32);
        o1 = MFMA16(ah1, vf1, o1);
        o1 = MFMA16(al1, vf1, o1);
    }

    #pragma unroll
    for (int r = 0; r < 4; ++r) {
        const int nn = lg * 4 + r;                       // C row = n, col = h = l15
        out[((size_t)(n0 + nn) * BATCH + b) * H + w * 16 + l15] = (o0[r] + o1[r]) * inv[nn];
    }
}

extern "C" void kernel_launch(void* const* d_in, const int* in_sizes, int n_in,
                              void* d_out, int out_size, void* d_ws, size_t ws_size,
                              hipStream_t stream)
{
    (void)in_sizes; (void)n_in; (void)out_size; (void)ws_size;
    const float* q    = (const float*)d_in[0];
    const float* k    = (const float*)d_in[1];
    const float* v    = (const float*)d_in[2];
    const float* mask = (const float*)d_in[3];
    const float* Wq   = (const float*)d_in[4];
    const float* bq   = (const float*)d_in[5];
    const float* Wk   = (const float*)d_in[6];
    const float* bk   = (const float*)d_in[7];
    const float* Wv   = (const float*)d_in[8];
    const float* bv   = (const float*)d_in[9];

    float* out  = (float*)d_out;                                  // [N,B,H]
    float* Aout = (float*)d_out + (size_t)NOBJ * BATCH * H;       // [B,N,N]

    // workspace: 5 bf16 arrays (42 MB) + bitmask (4.2 MB)
    const size_t S = (size_t)BATCH * NOBJ * H;
    unsigned short* qh = (unsigned short*)d_ws;
    unsigned short* ql = qh + S;
    unsigned short* kh = ql + S;
    unsigned short* kl = kh + S;
    unsigned short* vt = kl + S;
    unsigned int* bits = (unsigned int*)(vt + S);

    prep_kernel<<<dim3(PACK_BLOCKS + 3 * BATCH * (NOBJ / 64)), 256, 0, stream>>>(
        mask, bits, q, k, v, Wq, bq, Wk, bk, Wv, bv, qh, ql, kh, kl, vt);
    attn_kernel<<<dim3((NOBJ / 16) * BATCH), 256, 0, stream>>>(
        qh, ql, kh, kl, vt, bits, out, Aout);
}

// Round 9
// 401.177 us; speedup vs baseline: 1.0201x; 1.0029x over previous
//
#include <hip/hip_runtime.h>

#define H 64
#define NOBJ 512
#define BATCH 128
#define PACK_BLOCKS ((BATCH * NOBJ * NOBJ) / 1024)   // 16384

typedef __attribute__((ext_vector_type(8))) short s16x8;
typedef __attribute__((ext_vector_type(4))) float f32x4;
typedef __attribute__((ext_vector_type(4))) unsigned short u16x4;
typedef __attribute__((ext_vector_type(8))) unsigned short u16x8;

__device__ __forceinline__ unsigned short f2bf(float f) {
    unsigned int u = __float_as_uint(f);
    u += 0x7FFFu + ((u >> 16) & 1u);          // round-to-nearest-even
    return (unsigned short)(u >> 16);
}
__device__ __forceinline__ float bf2f(unsigned short h) {
    return __uint_as_float((unsigned int)h << 16);
}

#define MFMA16(a, b, c) __builtin_amdgcn_mfma_f32_16x16x32_bf16(a, b, c, 0, 0, 0)
#define SBAR() __builtin_amdgcn_sched_barrier(0)

// ---------------- Kernel 1: fused prep = mask-pack + MFMA projections ----------
__global__ __launch_bounds__(256) void prep_kernel(
    const float* __restrict__ mask, unsigned int* __restrict__ bits,
    const float* __restrict__ q, const float* __restrict__ k, const float* __restrict__ v,
    const float* __restrict__ Wq, const float* __restrict__ bq,
    const float* __restrict__ Wk, const float* __restrict__ bk,
    const float* __restrict__ Wv, const float* __restrict__ bv,
    unsigned short* __restrict__ qh, unsigned short* __restrict__ ql,
    unsigned short* __restrict__ kh, unsigned short* __restrict__ kl,
    unsigned short* __restrict__ vt)
{
    __shared__ unsigned short vtile[64][72];   // proj: [h][n] tile; pack: nibble buf
    const int tid = threadIdx.x;

    if (blockIdx.x < PACK_BLOCKS) {
        // ---- mask pack: 1024 floats/block ----
        unsigned char* nib = (unsigned char*)&vtile[0][0];
        const size_t base = (size_t)blockIdx.x * 1024;
        const f32x4 f = __builtin_nontemporal_load((const f32x4*)(mask + base + (size_t)tid * 4));
        nib[tid] = (unsigned char)((unsigned)(f[0] != 0.0f)
                 | ((unsigned)(f[1] != 0.0f) << 1)
                 | ((unsigned)(f[2] != 0.0f) << 2)
                 | ((unsigned)(f[3] != 0.0f) << 3));
        __syncthreads();
        if (tid < 32) {
            unsigned int wv = 0;
            #pragma unroll
            for (int i = 0; i < 8; ++i)
                wv |= (unsigned int)nib[tid * 8 + i] << (4 * i);
            bits[base / 32 + tid] = wv;
        }
        return;
    }

    // ---- projections ----
    const int p   = blockIdx.x - PACK_BLOCKS;
    const int z   = p >> 10;              // 0..2 = {q,k,v}
    const int rem = p & 1023;
    const int b   = rem >> 3;
    const int n0  = (rem & 7) * 64;

    const float* x; const float* W; const float* bias;
    unsigned short* yh; unsigned short* yl;
    if (z == 0)      { x = q; W = Wq; bias = bq; yh = qh; yl = ql; }
    else if (z == 1) { x = k; W = Wk; bias = bk; yh = kh; yl = kl; }
    else             { x = v; W = Wv; bias = bv; yh = nullptr; yl = nullptr; }

    const int lane = tid & 63;
    const int wt   = tid >> 6;
    const int l15  = lane & 15;
    const int lg   = lane >> 4;

    // W fragments: lane = (row ht*16+l15, k = kc*32+lg*8+j), k contiguous
    s16x8 wfh[4][2], wfl[4][2];
    #pragma unroll
    for (int ht = 0; ht < 4; ++ht) {
        #pragma unroll
        for (int kc = 0; kc < 2; ++kc) {
            const float* wp = W + (ht * 16 + l15) * H + kc * 32 + lg * 8;
            float4 f0 = *(const float4*)wp;
            float4 f1 = *(const float4*)(wp + 4);
            float f[8] = {f0.x, f0.y, f0.z, f0.w, f1.x, f1.y, f1.z, f1.w};
            s16x8 hi8, lo8;
            #pragma unroll
            for (int j = 0; j < 8; ++j) {
                const unsigned short hb = f2bf(f[j]);
                hi8[j] = (short)hb;
                lo8[j] = (short)f2bf(f[j] - bf2f(hb));
            }
            wfh[ht][kc] = hi8; wfl[ht][kc] = lo8;
        }
    }

    // x fragments: n = n0+wt*16+l15, x is [N,B,H]
    const int n = n0 + wt * 16 + l15;
    const float* xr = x + ((size_t)n * BATCH + b) * H;
    s16x8 xfh[2], xfl[2];
    #pragma unroll
    for (int kc = 0; kc < 2; ++kc) {
        const float* xp = xr + kc * 32 + lg * 8;
        float4 f0 = *(const float4*)xp;
        float4 f1 = *(const float4*)(xp + 4);
        float f[8] = {f0.x, f0.y, f0.z, f0.w, f1.x, f1.y, f1.z, f1.w};
        s16x8 hi8, lo8;
        #pragma unroll
        for (int j = 0; j < 8; ++j) {
            const unsigned short hb = f2bf(f[j]);
            hi8[j] = (short)hb;
            lo8[j] = (short)f2bf(f[j] - bf2f(hb));
        }
        xfh[kc] = hi8; xfl[kc] = lo8;
    }

    if (z < 2) {
        // D[h][n]: lane holds h = ht*16+lg*4+r, n fixed -> coalesced u16x4 stores
        #pragma unroll
        for (int ht = 0; ht < 4; ++ht) {
            const float4 b4 = *(const float4*)(bias + ht * 16 + lg * 4);
            f32x4 acc = {b4.x, b4.y, b4.z, b4.w};
            acc = MFMA16(wfh[ht][0], xfh[0], acc);
            acc = MFMA16(wfh[ht][1], xfh[1], acc);
            acc = MFMA16(wfh[ht][0], xfl[0], acc);
            acc = MFMA16(wfh[ht][1], xfl[1], acc);
            acc = MFMA16(wfl[ht][0], xfh[0], acc);
            acc = MFMA16(wfl[ht][1], xfh[1], acc);
            u16x4 hv, lv;
            #pragma unroll
            for (int r = 0; r < 4; ++r) {
                const unsigned short hb = f2bf(acc[r]);
                hv[r] = hb;
                lv[r] = f2bf(acc[r] - bf2f(hb));
            }
            const size_t o = ((size_t)b * NOBJ + n) * H + ht * 16 + lg * 4;
            *(u16x4*)(yh + o) = hv;
            *(u16x4*)(yl + o) = lv;
        }
    } else {
        // D[n][h] -> LDS tile -> coalesced vt [B,H,N] stores
        #pragma unroll
        for (int ht = 0; ht < 4; ++ht) {
            const float bs = bias[ht * 16 + l15];
            f32x4 acc = {bs, bs, bs, bs};
            acc = MFMA16(xfh[0], wfh[ht][0], acc);
            acc = MFMA16(xfh[1], wfh[ht][1], acc);
            acc = MFMA16(xfl[0], wfh[ht][0], acc);
            acc = MFMA16(xfl[1], wfh[ht][1], acc);
            acc = MFMA16(xfh[0], wfl[ht][0], acc);
            acc = MFMA16(xfh[1], wfl[ht][1], acc);
            u16x4 hv;
            #pragma unroll
            for (int r = 0; r < 4; ++r) hv[r] = f2bf(acc[r]);
            *(u16x4*)&vtile[ht * 16 + l15][wt * 16 + lg * 4] = hv;
        }
        __syncthreads();
        const int h = tid >> 2, nc = (tid & 3) * 16;
        const u16x8 d0 = *(const u16x8*)&vtile[h][nc];
        const u16x8 d1 = *(const u16x8*)&vtile[h][nc + 8];
        unsigned short* dst = vt + ((size_t)b * H + h) * NOBJ + n0 + nc;
        *(u16x8*)dst = d0;
        *(u16x8*)(dst + 8) = d1;
    }
}

// ---------------- Kernel 2: MFMA attention, pinned software pipeline ----------
// 1-D grid 4096, XCD-colocating swizzle (FETCH 109->23 MB, R6).
// R4-R8 lesson: the compiler sinks prefetch loads to their uses at ANY register
// budget (VGPR stuck at 64 -> zero memory-level parallelism -> ~40 serial
// ~300cy loads = the 115us floor). Fix: named-register double buffers with
// __builtin_amdgcn_sched_barrier(0) fences pinning load issue ahead of compute.
// ev[] dropped (A-write reconstructs e = hi+lo from strips, R2-proven) to keep
// VGPR ~<=128 so LDS-limited 4 blocks/CU occupancy is preserved.
__global__ __launch_bounds__(256, 2) void attn_kernel(
    const unsigned short* __restrict__ qh, const unsigned short* __restrict__ ql,
    const unsigned short* __restrict__ kh, const unsigned short* __restrict__ kl,
    const unsigned short* __restrict__ vt, const unsigned int* __restrict__ bits,
    float* __restrict__ out, float* __restrict__ Aout)
{
    __shared__ unsigned short sch[16][520];  // e hi strip, stride 260 dwords
    __shared__ unsigned short scl[16][520];  // e lo strip
    __shared__ float rsum[4][16];
    __shared__ float inv[16];

    const int tid  = threadIdx.x;
    const int lane = tid & 63;
    const int w    = tid >> 6;
    const int l15  = lane & 15;
    const int lg   = lane >> 4;

    const int orig = blockIdx.x;
    const int xcd  = orig & 7;
    const int s    = orig >> 3;
    const int b    = xcd + 8 * (s >> 5);
    const int n0   = (s & 31) * 16;

    // q fragments (B-operand): col n = l15, k = h contiguous
    const size_t qoff = ((size_t)b * NOBJ + n0 + l15) * H + lg * 8;
    const s16x8 qfh0 = *(const s16x8*)(qh + qoff);
    const s16x8 qfh1 = *(const s16x8*)(qh + qoff + 32);
    const s16x8 qfl0 = *(const s16x8*)(ql + qoff);
    const s16x8 qfl1 = *(const s16x8*)(ql + qoff + 32);

    const unsigned short* khp = kh + ((size_t)b * NOBJ + w * 128 + l15) * H + lg * 8;
    const unsigned short* klp = kl + ((size_t)b * NOBJ + w * 128 + l15) * H + lg * 8;

    // one uint4 = this row's mask bits for cols [w*128, w*128+128)
    const uint4 mw = *(const uint4*)(bits + ((size_t)b * NOBJ + n0 + l15) * (NOBJ / 32) + w * 4);
    const unsigned mwa[4] = {mw.x, mw.y, mw.z, mw.w};

    float rp = 0.0f;

    // ---- score phase: 2-mt pairs, kA/kB double buffer, sched_barrier-pinned ----
    s16x8 kA[2][4], kB[2][4];

#define LOADP(dst, mt0)                                                   \
    do {                                                                  \
        dst[0][0] = *(const s16x8*)(khp + (mt0) * 16 * H);                \
        dst[0][1] = *(const s16x8*)(khp + (mt0) * 16 * H + 32);           \
        dst[0][2] = *(const s16x8*)(klp + (mt0) * 16 * H);                \
        dst[0][3] = *(const s16x8*)(klp + (mt0) * 16 * H + 32);           \
        dst[1][0] = *(const s16x8*)(khp + ((mt0) + 1) * 16 * H);          \
        dst[1][1] = *(const s16x8*)(khp + ((mt0) + 1) * 16 * H + 32);     \
        dst[1][2] = *(const s16x8*)(klp + ((mt0) + 1) * 16 * H);          \
        dst[1][3] = *(const s16x8*)(klp + ((mt0) + 1) * 16 * H + 32);     \
    } while (0)

#define SCORE1(src, i, mt)                                                \
    do {                                                                  \
        f32x4 acc = {0.0f, 0.0f, 0.0f, 0.0f};                             \
        acc = MFMA16(src[i][0], qfh0, acc);                               \
        acc = MFMA16(src[i][1], qfh1, acc);                               \
        acc = MFMA16(src[i][0], qfl0, acc);                               \
        acc = MFMA16(src[i][1], qfl1, acc);                               \
        acc = MFMA16(src[i][2], qfh0, acc);                               \
        acc = MFMA16(src[i][3], qfh1, acc);                               \
        const unsigned wsel = mwa[(mt) >> 1] >> ((((mt) & 1) << 4) + (lg << 2)); \
        u16x4 hv, lv;                                                     \
        _Pragma("unroll")                                                 \
        for (int r = 0; r < 4; ++r) {                                     \
            const float ex = __expf(acc[r] * 0.125f);                     \
            const float e = ((wsel >> r) & 1u) ? ex : 0.0f;               \
            rp += e;                                                      \
            const unsigned short hb = f2bf(e);                            \
            hv[r] = hb;                                                   \
            lv[r] = f2bf(e - bf2f(hb));                                   \
        }                                                                 \
        const int mo = w * 128 + (mt) * 16 + lg * 4;                      \
        *(u16x4*)&sch[l15][mo] = hv;                                      \
        *(u16x4*)&scl[l15][mo] = lv;                                      \
    } while (0)

    LOADP(kA, 0);
    SBAR();
    LOADP(kB, 2);
    SBAR();
    SCORE1(kA, 0, 0); SCORE1(kA, 1, 1);
    LOADP(kA, 4);
    SBAR();
    SCORE1(kB, 0, 2); SCORE1(kB, 1, 3);
    LOADP(kB, 6);
    SBAR();
    SCORE1(kA, 0, 4); SCORE1(kA, 1, 5);
    SCORE1(kB, 0, 6); SCORE1(kB, 1, 7);
#undef LOADP
#undef SCORE1

    // prefetch first vt pair for AV before the reduction barriers
    const unsigned short* vtp = vt + ((size_t)b * H + w * 16 + l15) * NOBJ + lg * 8;
    s16x8 vA0, vA1, vB0, vB1;
    vA0 = *(const s16x8*)(vtp);
    vA1 = *(const s16x8*)(vtp + 32);
    SBAR();

    rp += __shfl_xor(rp, 16);
    rp += __shfl_xor(rp, 32);
    if (lane < 16) rsum[w][lane] = rp;
    __syncthreads();
    if (tid < 16) {
        const float sv = (rsum[0][tid] + rsum[1][tid]) + (rsum[2][tid] + rsum[3][tid]);
        inv[tid] = 1.0f / (sv == 0.0f ? 1.0f : sv);
    }
    __syncthreads();

    // A write: e = hi + lo reconstructed from strips (R2-proven), float4 per lane
    {
        const float iv = inv[l15];
        float* Arow = Aout + ((size_t)b * NOBJ + n0 + l15) * NOBJ + w * 128 + lg * 4;
        #pragma unroll
        for (int mt = 0; mt < 8; ++mt) {
            const int mo = w * 128 + mt * 16 + lg * 4;
            const u16x4 hv = *(const u16x4*)&sch[l15][mo];
            const u16x4 lv = *(const u16x4*)&scl[l15][mo];
            float4 a4;
            a4.x = (bf2f(hv[0]) + bf2f(lv[0])) * iv;
            a4.y = (bf2f(hv[1]) + bf2f(lv[1])) * iv;
            a4.z = (bf2f(hv[2]) + bf2f(lv[2])) * iv;
            a4.w = (bf2f(hv[3]) + bf2f(lv[3])) * iv;
            *(float4*)(Arow + mt * 16) = a4;
        }
    }

    // ---- AV phase: vt double-buffered one ks-pair ahead, pinned ----
    f32x4 o0 = {0.0f, 0.0f, 0.0f, 0.0f}, o1 = {0.0f, 0.0f, 0.0f, 0.0f};

#define LOADV(d0, d1, ks)                                                 \
    do {                                                                  \
        d0 = *(const s16x8*)(vtp + (ks) * 32);                            \
        d1 = *(const s16x8*)(vtp + (ks) * 32 + 32);                       \
    } while (0)

#define AVSTEP(v0, v1, ks)                                                \
    do {                                                                  \
        const int mk = (ks) * 32 + lg * 8;                                \
        const s16x8 ah0 = *(const s16x8*)&sch[l15][mk];                   \
        const s16x8 al0 = *(const s16x8*)&scl[l15][mk];                   \
        o0 = MFMA16(ah0, v0, o0);                                         \
        o0 = MFMA16(al0, v0, o0);                                         \
        const s16x8 ah1 = *(const s16x8*)&sch[l15][mk + 32];              \
        const s16x8 al1 = *(const s16x8*)&scl[l15][mk + 32];              \
        o1 = MFMA16(ah1, v1, o1);                                         \
        o1 = MFMA16(al1, v1, o1);                                         \
    } while (0)

    LOADV(vB0, vB1, 2);  SBAR();
    AVSTEP(vA0, vA1, 0);
    LOADV(vA0, vA1, 4);  SBAR();
    AVSTEP(vB0, vB1, 2);
    LOADV(vB0, vB1, 6);  SBAR();
    AVSTEP(vA0, vA1, 4);
    LOADV(vA0, vA1, 8);  SBAR();
    AVSTEP(vB0, vB1, 6);
    LOADV(vB0, vB1, 10); SBAR();
    AVSTEP(vA0, vA1, 8);
    LOADV(vA0, vA1, 12); SBAR();
    AVSTEP(vB0, vB1, 10);
    LOADV(vB0, vB1, 14); SBAR();
    AVSTEP(vA0, vA1, 12);
    AVSTEP(vB0, vB1, 14);
#undef LOADV
#undef AVSTEP

    #pragma unroll
    for (int r = 0; r < 4; ++r) {
        const int nn = lg * 4 + r;                       // C row = n, col = h = l15
        out[((size_t)(n0 + nn) * BATCH + b) * H + w * 16 + l15] = (o0[r] + o1[r]) * inv[nn];
    }
}

extern "C" void kernel_launch(void* const* d_in, const int* in_sizes, int n_in,
                              void* d_out, int out_size, void* d_ws, size_t ws_size,
                              hipStream_t stream)
{
    (void)in_sizes; (void)n_in; (void)out_size; (void)ws_size;
    const float* q    = (const float*)d_in[0];
    const float* k    = (const float*)d_in[1];
    const float* v    = (const float*)d_in[2];
    const float* mask = (const float*)d_in[3];
    const float* Wq   = (const float*)d_in[4];
    const float* bq   = (const float*)d_in[5];
    const float* Wk   = (const float*)d_in[6];
    const float* bk   = (const float*)d_in[7];
    const float* Wv   = (const float*)d_in[8];
    const float* bv   = (const float*)d_in[9];

    float* out  = (float*)d_out;                                  // [N,B,H]
    float* Aout = (float*)d_out + (size_t)NOBJ * BATCH * H;       // [B,N,N]

    // workspace: 5 bf16 arrays (42 MB) + bitmask (4.2 MB)
    const size_t S = (size_t)BATCH * NOBJ * H;
    unsigned short* qh = (unsigned short*)d_ws;
    unsigned short* ql = qh + S;
    unsigned short* kh = ql + S;
    unsigned short* kl = kh + S;
    unsigned short* vt = kl + S;
    unsigned int* bits = (unsigned int*)(vt + S);

    prep_kernel<<<dim3(PACK_BLOCKS + 3 * BATCH * (NOBJ / 64)), 256, 0, stream>>>(
        mask, bits, q, k, v, Wq, bq, Wk, bk, Wv, bv, qh, ql, kh, kl, vt);
    attn_kernel<<<dim3((NOBJ / 16) * BATCH), 256, 0, stream>>>(
        qh, ql, kh, kl, vt, bits, out, Aout);
}

// Round 10
// 362.004 us; speedup vs baseline: 1.1305x; 1.1082x over previous
//
#include <hip/hip_runtime.h>

#define H 64
#define NOBJ 512
#define BATCH 128
#define PACK_BLOCKS ((BATCH * NOBJ * NOBJ) / 1024)   // 16384

typedef __attribute__((ext_vector_type(8))) short s16x8;
typedef __attribute__((ext_vector_type(4))) float f32x4;
typedef __attribute__((ext_vector_type(4))) unsigned short u16x4;
typedef __attribute__((ext_vector_type(8))) unsigned short u16x8;

__device__ __forceinline__ unsigned short f2bf(float f) {
    unsigned int u = __float_as_uint(f);
    u += 0x7FFFu + ((u >> 16) & 1u);          // round-to-nearest-even
    return (unsigned short)(u >> 16);
}
__device__ __forceinline__ float bf2f(unsigned short h) {
    return __uint_as_float((unsigned int)h << 16);
}

#define MFMA16(a, b, c) __builtin_amdgcn_mfma_f32_16x16x32_bf16(a, b, c, 0, 0, 0)
#define SBAR() __builtin_amdgcn_sched_barrier(0)

// Fragment-major layouts (R10): every attn global load is base + lane*16B.
//   q/k arrays: [b][tile(32)][kc(2)][lane(64)][8 shorts]   (tile = n/16 resp m/16)
//   v array:    [b][hw(4)][ks(16)][lane(64)][8 shorts]     (hw = h/16, ks = n/32)
// Fragment at lane = lg*16 + l15: rows l15, k-dim lg*8..+8 (+32 for kc=1).

// ---------------- Kernel 1: fused prep = mask-pack + MFMA projections ----------
__global__ __launch_bounds__(256) void prep_kernel(
    const float* __restrict__ mask, unsigned int* __restrict__ bits,
    const float* __restrict__ q, const float* __restrict__ k, const float* __restrict__ v,
    const float* __restrict__ Wq, const float* __restrict__ bq,
    const float* __restrict__ Wk, const float* __restrict__ bk,
    const float* __restrict__ Wv, const float* __restrict__ bv,
    unsigned short* __restrict__ qhf, unsigned short* __restrict__ qlf,
    unsigned short* __restrict__ khf, unsigned short* __restrict__ klf,
    unsigned short* __restrict__ vtf)
{
    __shared__ unsigned short vtile[64][72];   // proj: [h][n] tile; pack: nibble buf
    const int tid = threadIdx.x;

    if (blockIdx.x < PACK_BLOCKS) {
        // ---- mask pack: 1024 floats/block ----
        unsigned char* nib = (unsigned char*)&vtile[0][0];
        const size_t base = (size_t)blockIdx.x * 1024;
        const f32x4 f = __builtin_nontemporal_load((const f32x4*)(mask + base + (size_t)tid * 4));
        nib[tid] = (unsigned char)((unsigned)(f[0] != 0.0f)
                 | ((unsigned)(f[1] != 0.0f) << 1)
                 | ((unsigned)(f[2] != 0.0f) << 2)
                 | ((unsigned)(f[3] != 0.0f) << 3));
        __syncthreads();
        if (tid < 32) {
            unsigned int wv = 0;
            #pragma unroll
            for (int i = 0; i < 8; ++i)
                wv |= (unsigned int)nib[tid * 8 + i] << (4 * i);
            bits[base / 32 + tid] = wv;
        }
        return;
    }

    // ---- projections ----
    const int p   = blockIdx.x - PACK_BLOCKS;
    const int z   = p >> 10;              // 0..2 = {q,k,v}
    const int rem = p & 1023;
    const int b   = rem >> 3;
    const int n0  = (rem & 7) * 64;

    const float* x; const float* W; const float* bias;
    unsigned short* yh; unsigned short* yl;
    if (z == 0)      { x = q; W = Wq; bias = bq; yh = qhf; yl = qlf; }
    else if (z == 1) { x = k; W = Wk; bias = bk; yh = khf; yl = klf; }
    else             { x = v; W = Wv; bias = bv; yh = nullptr; yl = nullptr; }

    const int lane = tid & 63;
    const int wt   = tid >> 6;
    const int pl   = lane & 15;   // n-local within wave tile
    const int pg   = lane >> 4;   // h-quad group

    // W fragments: lane = (row ht*16+pl, k = kc*32+pg*8+j), k contiguous
    s16x8 wfh[4][2], wfl[4][2];
    #pragma unroll
    for (int ht = 0; ht < 4; ++ht) {
        #pragma unroll
        for (int kc = 0; kc < 2; ++kc) {
            const float* wp = W + (ht * 16 + pl) * H + kc * 32 + pg * 8;
            float4 f0 = *(const float4*)wp;
            float4 f1 = *(const float4*)(wp + 4);
            float f[8] = {f0.x, f0.y, f0.z, f0.w, f1.x, f1.y, f1.z, f1.w};
            s16x8 hi8, lo8;
            #pragma unroll
            for (int j = 0; j < 8; ++j) {
                const unsigned short hb = f2bf(f[j]);
                hi8[j] = (short)hb;
                lo8[j] = (short)f2bf(f[j] - bf2f(hb));
            }
            wfh[ht][kc] = hi8; wfl[ht][kc] = lo8;
        }
    }

    // x fragments: n = n0+wt*16+pl, x is [N,B,H]
    const int n = n0 + wt * 16 + pl;
    const float* xr = x + ((size_t)n * BATCH + b) * H;
    s16x8 xfh[2], xfl[2];
    #pragma unroll
    for (int kc = 0; kc < 2; ++kc) {
        const float* xp = xr + kc * 32 + pg * 8;
        float4 f0 = *(const float4*)xp;
        float4 f1 = *(const float4*)(xp + 4);
        float f[8] = {f0.x, f0.y, f0.z, f0.w, f1.x, f1.y, f1.z, f1.w};
        s16x8 hi8, lo8;
        #pragma unroll
        for (int j = 0; j < 8; ++j) {
            const unsigned short hb = f2bf(f[j]);
            hi8[j] = (short)hb;
            lo8[j] = (short)f2bf(f[j] - bf2f(hb));
        }
        xfh[kc] = hi8; xfl[kc] = lo8;
    }

    if (z < 2) {
        // D[h][n]: lane holds h = ht*16+pg*4+r (quad g = ht*4+pg), n fixed.
        // Store fragment-major: tile = b*32 + n0/16 + wt; off = (tile*2+kc)*512
        //   + (lgA*16+pl)*8 + jh*4, with kc=g>>3, lgA=(g>>1)&3, jh=g&1.
        // Per ht the wave's 64 stores cover 512 contiguous bytes.
        #pragma unroll
        for (int ht = 0; ht < 4; ++ht) {
            const float4 b4 = *(const float4*)(bias + ht * 16 + pg * 4);
            f32x4 acc = {b4.x, b4.y, b4.z, b4.w};
            acc = MFMA16(wfh[ht][0], xfh[0], acc);
            acc = MFMA16(wfh[ht][1], xfh[1], acc);
            acc = MFMA16(wfh[ht][0], xfl[0], acc);
            acc = MFMA16(wfh[ht][1], xfl[1], acc);
            acc = MFMA16(wfl[ht][0], xfh[0], acc);
            acc = MFMA16(wfl[ht][1], xfh[1], acc);
            u16x4 hv, lv;
            #pragma unroll
            for (int r = 0; r < 4; ++r) {
                const unsigned short hb = f2bf(acc[r]);
                hv[r] = hb;
                lv[r] = f2bf(acc[r] - bf2f(hb));
            }
            const int g   = ht * 4 + pg;
            const int kc  = g >> 3;
            const int lgA = (g >> 1) & 3;
            const int jh  = g & 1;
            const size_t off = ((size_t)(b * 32 + (n0 >> 4) + wt) * 2 + kc) * 512
                             + (lgA * 16 + pl) * 8 + jh * 4;
            *(u16x4*)(yh + off) = hv;
            *(u16x4*)(yl + off) = lv;
        }
    } else {
        // D[n][h] -> LDS tile -> fragment-major vtf stores
        #pragma unroll
        for (int ht = 0; ht < 4; ++ht) {
            const float bs = bias[ht * 16 + pl];
            f32x4 acc = {bs, bs, bs, bs};
            acc = MFMA16(xfh[0], wfh[ht][0], acc);
            acc = MFMA16(xfh[1], wfh[ht][1], acc);
            acc = MFMA16(xfl[0], wfh[ht][0], acc);
            acc = MFMA16(xfl[1], wfh[ht][1], acc);
            acc = MFMA16(xfh[0], wfl[ht][0], acc);
            acc = MFMA16(xfh[1], wfl[ht][1], acc);
            u16x4 hv;
            #pragma unroll
            for (int r = 0; r < 4; ++r) hv[r] = f2bf(acc[r]);
            *(u16x4*)&vtile[ht * 16 + pl][wt * 16 + pg * 4] = hv;
        }
        __syncthreads();
        // gather: chunk c -> (hw = c>>7, ksl = (c>>6)&1, laneA = c&63);
        // fragment (laneA = lgA*16+l15) = v[h = hw*16+l15][n = ks*32+lgA*8..+8]
        #pragma unroll
        for (int i = 0; i < 2; ++i) {
            const int c     = tid * 2 + i;
            const int laneA = c & 63;
            const int ksl   = (c >> 6) & 1;
            const int hw    = c >> 7;
            const u16x8 d = *(const u16x8*)&vtile[hw * 16 + (laneA & 15)]
                                                 [ksl * 32 + ((laneA >> 4) & 3) * 8];
            *(u16x8*)(vtf + (((size_t)(b * 4 + hw) * 16) + (n0 >> 5) + ksl) * 512
                          + laneA * 8) = d;
        }
    }
}

// ---------------- Kernel 2: MFMA attention, coalesced fragment loads ----------
// 1-D grid 4096, XCD-colocating swizzle (FETCH 109->23 MB, R6) + R9's pinned
// pipeline. R10: all k/q/vt loads are fragment-major -> base + lane*16B (one
// 1KB contiguous wave-load = 8 full lines, vs 16 partial 64B scatters before);
// A-write is block-cooperative row-major (full-line stores).
__global__ __launch_bounds__(256, 2) void attn_kernel(
    const unsigned short* __restrict__ qhf, const unsigned short* __restrict__ qlf,
    const unsigned short* __restrict__ khf, const unsigned short* __restrict__ klf,
    const unsigned short* __restrict__ vtf, const unsigned int* __restrict__ bits,
    float* __restrict__ out, float* __restrict__ Aout)
{
    __shared__ unsigned short sch[16][520];  // e hi strip, stride 260 dwords
    __shared__ unsigned short scl[16][520];  // e lo strip
    __shared__ float rsum[4][16];
    __shared__ float inv[16];

    const int tid  = threadIdx.x;
    const int lane = tid & 63;
    const int w    = tid >> 6;
    const int l15  = lane & 15;
    const int lg   = lane >> 4;

    const int orig = blockIdx.x;
    const int xcd  = orig & 7;
    const int s    = orig >> 3;
    const int b    = xcd + 8 * (s >> 5);
    const int nt   = s & 31;            // n-tile index
    const int n0   = nt * 16;

    // q fragments: coalesced (base + lane*16B)
    const unsigned short* qbase_h = qhf + ((size_t)(b * 32 + nt)) * 1024 + lane * 8;
    const unsigned short* qbase_l = qlf + ((size_t)(b * 32 + nt)) * 1024 + lane * 8;
    const s16x8 qfh0 = *(const s16x8*)(qbase_h);
    const s16x8 qfh1 = *(const s16x8*)(qbase_h + 512);
    const s16x8 qfl0 = *(const s16x8*)(qbase_l);
    const s16x8 qfl1 = *(const s16x8*)(qbase_l + 512);

    const unsigned short* khfp = khf + ((size_t)(b * 32 + w * 8)) * 1024 + lane * 8;
    const unsigned short* klfp = klf + ((size_t)(b * 32 + w * 8)) * 1024 + lane * 8;

    // one uint4 = this row's mask bits for cols [w*128, w*128+128)
    const uint4 mw = *(const uint4*)(bits + ((size_t)b * NOBJ + n0 + l15) * (NOBJ / 32) + w * 4);
    const unsigned mwa[4] = {mw.x, mw.y, mw.z, mw.w};

    float rp = 0.0f;

    // ---- score phase: 2-mt pairs, kA/kB double buffer, sched_barrier-pinned ----
    s16x8 kA[2][4], kB[2][4];

#define LOADP(dst, mt0)                                                   \
    do {                                                                  \
        dst[0][0] = *(const s16x8*)(khfp + (mt0) * 1024);                 \
        dst[0][1] = *(const s16x8*)(khfp + (mt0) * 1024 + 512);           \
        dst[0][2] = *(const s16x8*)(klfp + (mt0) * 1024);                 \
        dst[0][3] = *(const s16x8*)(klfp + (mt0) * 1024 + 512);           \
        dst[1][0] = *(const s16x8*)(khfp + ((mt0) + 1) * 1024);           \
        dst[1][1] = *(const s16x8*)(khfp + ((mt0) + 1) * 1024 + 512);     \
        dst[1][2] = *(const s16x8*)(klfp + ((mt0) + 1) * 1024);           \
        dst[1][3] = *(const s16x8*)(klfp + ((mt0) + 1) * 1024 + 512);     \
    } while (0)

#define SCORE1(src, i, mt)                                                \
    do {                                                                  \
        f32x4 acc = {0.0f, 0.0f, 0.0f, 0.0f};                             \
        acc = MFMA16(src[i][0], qfh0, acc);                               \
        acc = MFMA16(src[i][1], qfh1, acc);                               \
        acc = MFMA16(src[i][0], qfl0, acc);                               \
        acc = MFMA16(src[i][1], qfl1, acc);                               \
        acc = MFMA16(src[i][2], qfh0, acc);                               \
        acc = MFMA16(src[i][3], qfh1, acc);                               \
        const unsigned wsel = mwa[(mt) >> 1] >> ((((mt) & 1) << 4) + (lg << 2)); \
        u16x4 hv, lv;                                                     \
        _Pragma("unroll")                                                 \
        for (int r = 0; r < 4; ++r) {                                     \
            const float ex = __expf(acc[r] * 0.125f);                     \
            const float e = ((wsel >> r) & 1u) ? ex : 0.0f;               \
            rp += e;                                                      \
            const unsigned short hb = f2bf(e);                            \
            hv[r] = hb;                                                   \
            lv[r] = f2bf(e - bf2f(hb));                                   \
        }                                                                 \
        const int mo = w * 128 + (mt) * 16 + lg * 4;                      \
        *(u16x4*)&sch[l15][mo] = hv;                                      \
        *(u16x4*)&scl[l15][mo] = lv;                                      \
    } while (0)

    LOADP(kA, 0);
    SBAR();
    LOADP(kB, 2);
    SBAR();
    SCORE1(kA, 0, 0); SCORE1(kA, 1, 1);
    LOADP(kA, 4);
    SBAR();
    SCORE1(kB, 0, 2); SCORE1(kB, 1, 3);
    LOADP(kB, 6);
    SBAR();
    SCORE1(kA, 0, 4); SCORE1(kA, 1, 5);
    SCORE1(kB, 0, 6); SCORE1(kB, 1, 7);
#undef LOADP
#undef SCORE1

    // prefetch first vt pair for AV before the reduction barriers (coalesced)
    const unsigned short* vtfp = vtf + ((size_t)(b * 4 + w) * 16) * 512 + lane * 8;
    s16x8 vA0, vA1, vB0, vB1;
    vA0 = *(const s16x8*)(vtfp);
    vA1 = *(const s16x8*)(vtfp + 512);
    SBAR();

    rp += __shfl_xor(rp, 16);
    rp += __shfl_xor(rp, 32);
    if (lane < 16) rsum[w][lane] = rp;
    __syncthreads();
    if (tid < 16) {
        const float sv = (rsum[0][tid] + rsum[1][tid]) + (rsum[2][tid] + rsum[3][tid]);
        inv[tid] = 1.0f / (sv == 0.0f ? 1.0f : sv);
    }
    __syncthreads();

    // A write: block-cooperative row-major -> fully coalesced full-line stores.
    // thread = (row = tid>>4, 32-col chunk = (tid&15)*32); e = hi+lo (R2-proven).
    {
        const int row = tid >> 4, t16 = tid & 15;
        const float iv = inv[row];
        float* Arow = Aout + ((size_t)b * NOBJ + n0 + row) * NOBJ + t16 * 32;
        #pragma unroll
        for (int cc = 0; cc < 4; ++cc) {
            const u16x8 hv = *(const u16x8*)&sch[row][t16 * 32 + cc * 8];
            const u16x8 lv = *(const u16x8*)&scl[row][t16 * 32 + cc * 8];
            float4 a0, a1;
            a0.x = (bf2f(hv[0]) + bf2f(lv[0])) * iv;
            a0.y = (bf2f(hv[1]) + bf2f(lv[1])) * iv;
            a0.z = (bf2f(hv[2]) + bf2f(lv[2])) * iv;
            a0.w = (bf2f(hv[3]) + bf2f(lv[3])) * iv;
            a1.x = (bf2f(hv[4]) + bf2f(lv[4])) * iv;
            a1.y = (bf2f(hv[5]) + bf2f(lv[5])) * iv;
            a1.z = (bf2f(hv[6]) + bf2f(lv[6])) * iv;
            a1.w = (bf2f(hv[7]) + bf2f(lv[7])) * iv;
            *(float4*)(Arow + cc * 8)     = a0;
            *(float4*)(Arow + cc * 8 + 4) = a1;
        }
    }

    // ---- AV phase: vt double-buffered one ks-pair ahead, pinned, coalesced ----
    f32x4 o0 = {0.0f, 0.0f, 0.0f, 0.0f}, o1 = {0.0f, 0.0f, 0.0f, 0.0f};

#define LOADV(d0, d1, ks)                                                 \
    do {                                                                  \
        d0 = *(const s16x8*)(vtfp + (ks) * 512);                          \
        d1 = *(const s16x8*)(vtfp + ((ks) + 1) * 512);                    \
    } while (0)

#define AVSTEP(v0, v1, ks)                                                \
    do {                                                                  \
        const int mk = (ks) * 32 + lg * 8;                                \
        const s16x8 ah0 = *(const s16x8*)&sch[l15][mk];                   \
        const s16x8 al0 = *(const s16x8*)&scl[l15][mk];                   \
        o0 = MFMA16(ah0, v0, o0);                                         \
        o0 = MFMA16(al0, v0, o0);                                         \
        const s16x8 ah1 = *(const s16x8*)&sch[l15][mk + 32];              \
        const s16x8 al1 = *(const s16x8*)&scl[l15][mk + 32];              \
        o1 = MFMA16(ah1, v1, o1);                                         \
        o1 = MFMA16(al1, v1, o1);                                         \
    } while (0)

    LOADV(vB0, vB1, 2);  SBAR();
    AVSTEP(vA0, vA1, 0);
    LOADV(vA0, vA1, 4);  SBAR();
    AVSTEP(vB0, vB1, 2);
    LOADV(vB0, vB1, 6);  SBAR();
    AVSTEP(vA0, vA1, 4);
    LOADV(vA0, vA1, 8);  SBAR();
    AVSTEP(vB0, vB1, 6);
    LOADV(vB0, vB1, 10); SBAR();
    AVSTEP(vA0, vA1, 8);
    LOADV(vA0, vA1, 12); SBAR();
    AVSTEP(vB0, vB1, 10);
    LOADV(vB0, vB1, 14); SBAR();
    AVSTEP(vA0, vA1, 12);
    AVSTEP(vB0, vB1, 14);
#undef LOADV
#undef AVSTEP

    #pragma unroll
    for (int r = 0; r < 4; ++r) {
        const int nn = lg * 4 + r;                       // C row = n, col = h = l15
        out[((size_t)(n0 + nn) * BATCH + b) * H + w * 16 + l15] = (o0[r] + o1[r]) * inv[nn];
    }
}

extern "C" void kernel_launch(void* const* d_in, const int* in_sizes, int n_in,
                              void* d_out, int out_size, void* d_ws, size_t ws_size,
                              hipStream_t stream)
{
    (void)in_sizes; (void)n_in; (void)out_size; (void)ws_size;
    const float* q    = (const float*)d_in[0];
    const float* k    = (const float*)d_in[1];
    const float* v    = (const float*)d_in[2];
    const float* mask = (const float*)d_in[3];
    const float* Wq   = (const float*)d_in[4];
    const float* bq   = (const float*)d_in[5];
    const float* Wk   = (const float*)d_in[6];
    const float* bk   = (const float*)d_in[7];
    const float* Wv   = (const float*)d_in[8];
    const float* bv   = (const float*)d_in[9];

    float* out  = (float*)d_out;                                  // [N,B,H]
    float* Aout = (float*)d_out + (size_t)NOBJ * BATCH * H;       // [B,N,N]

    // workspace: 5 bf16 fragment-major arrays (42 MB) + bitmask (4.2 MB)
    const size_t S = (size_t)BATCH * NOBJ * H;
    unsigned short* qhf = (unsigned short*)d_ws;
    unsigned short* qlf = qhf + S;
    unsigned short* khf = qlf + S;
    unsigned short* klf = khf + S;
    unsigned short* vtf = klf + S;
    unsigned int* bits = (unsigned int*)(vtf + S);

    prep_kernel<<<dim3(PACK_BLOCKS + 3 * BATCH * (NOBJ / 64)), 256, 0, stream>>>(
        mask, bits, q, k, v, Wq, bq, Wk, bk, Wv, bv, qhf, qlf, khf, klf, vtf);
    attn_kernel<<<dim3((NOBJ / 16) * BATCH), 256, 0, stream>>>(
        qhf, qlf, khf, klf, vtf, bits, out, Aout);
}